// Round 15
// baseline (150.481 us; speedup 1.0000x reference)
//
#include <hip/hip_runtime.h>
#include <hip/hip_bf16.h>

typedef unsigned short u16;
typedef unsigned int u32;
typedef __bf16 bf16x8 __attribute__((ext_vector_type(8)));
typedef float f32x4 __attribute__((ext_vector_type(4)));
typedef float f32x16 __attribute__((ext_vector_type(16)));

static constexpr int kS = 2048;
static constexpr int kB = 2;
static constexpr int kD = 1024;
static constexpr int kDH = 64;
static constexpr int kM = kS * kB;  // 4096 rows of (s,b)
static constexpr float kScale = 0.125f;   // 1/sqrt(64)
static constexpr float kLog2e = 1.44269504088896340736f;

__device__ __forceinline__ u16 f2bf(float f) {
  return __builtin_bit_cast(u16, static_cast<__bf16>(f));
}

__device__ __forceinline__ u32 pack2(float lo, float hi) {
  union { u16 h[2]; u32 u; } x;
  x.h[0] = f2bf(lo); x.h[1] = f2bf(hi);
  return x.u;
}

__device__ __forceinline__ void permswap(u32& a, u32& b) {
  asm volatile("v_permlane32_swap_b32 %0, %1" : "+v"(a), "+v"(b));
}

// exact hardware exp2 (1 instruction; libm exp2f carries range-fixup ops)
__device__ __forceinline__ float exp2_hw(float x) {
  float r;
  asm("v_exp_f32 %0, %1" : "=v"(r) : "v"(x));
  return r;
}

__device__ __forceinline__ void load_lds16(const void* g, void* l) {
  __builtin_amdgcn_global_load_lds(
      (const __attribute__((address_space(1))) void*)g,
      (__attribute__((address_space(3))) void*)l, 16, 0, 0);
}

// ---------------- fused casts fp32 -> bf16 (one launch) ----------------
__global__ void cast_all(const float* __restrict__ x,
                         const float* __restrict__ Wq, const float* __restrict__ Wk,
                         const float* __restrict__ Wv, const float* __restrict__ Wo,
                         u16* __restrict__ xb,
                         u16* __restrict__ dq, u16* __restrict__ dk,
                         u16* __restrict__ dv, u16* __restrict__ dw) {
  const int bid = blockIdx.x;
  const float* src; u16* dst; int i;
  if (bid < 4096) {
    src = x; dst = xb;
    i = (bid * 256 + (int)threadIdx.x) * 4;
  } else {
    const int r = bid - 4096;
    switch (r >> 10) {
      case 0: src = Wq; dst = dq; break;
      case 1: src = Wk; dst = dk; break;
      case 2: src = Wv; dst = dv; break;
      default: src = Wo; dst = dw; break;
    }
    i = ((r & 1023) * 256 + (int)threadIdx.x) * 4;
  }
  const float4 v = *reinterpret_cast<const float4*>(src + i);
  ushort4 o;
  o.x = f2bf(v.x); o.y = f2bf(v.y); o.z = f2bf(v.z); o.w = f2bf(v.w);
  *reinterpret_cast<ushort4*>(dst + i) = o;
}

// ---------------- GEMM 128x64 tile, double-buffered, 1 barrier per K-step ----------
// attn-R11 loop shape: prologue stage(0); per iter
//   [vmcnt(0) (own stage(ks) loads issued a full compute-phase ago -> near-free);
//    s_barrier; stage(ks+1) -> buf^1; ds_read + 8 MFMA from buf]
// WAR: stage(ks+1) writes buf[(ks+1)&1] whose readers (compute ks-1) all finished
// before barrier(ks). LDS 2*(16K A + 8K B) = 48 KiB -> 3 blocks/CU (24 waves).
// 8 waves as 4 row-groups x 2 col-groups; wave = 32x32 out (acc[2][2], 16 VGPR).
// MODE 0: bf16 row-major. MODE 1: f32 row-major. MODE 2: bf16 Vt-transposed.
template <int MODE>
__device__ __forceinline__ void gemm_body(
    const u16* __restrict__ A, const u16* __restrict__ W,
    const float* __restrict__ bias, void* __restrict__ Out,
    int M, int N, int K, float oscale) {
  __shared__ u16 As[2][128 * 64];
  __shared__ u16 Bs[2][64 * 64];
  const int tid = threadIdx.x;
  const int lane = tid & 63;
  const int wid = tid >> 6;            // 0..7
  const int wr = (wid >> 1) * 32;      // 4 row-groups
  const int wc = (wid & 1) * 32;       // 2 col-groups
  const int l15 = lane & 15;
  const int lg = lane >> 4;            // 0..3
  const int tm = blockIdx.x * 128;
  const int tn = blockIdx.y * 64;

  auto stage = [&](int k0, int buf) {
#pragma unroll
    for (int p = 0; p < 3; ++p) {
      const int c = p * 512 + tid;      // 0..1535 chunks of 16B
      if (c < 1024) {                   // A: 128 rows x 8 chunks
        const int row = c >> 3;
        const int scc = (c & 7) ^ (row & 7);
        load_lds16(A + (size_t)(tm + row) * K + k0 + scc * 8, &As[buf][c * 8]);
      } else {                          // B: 64 rows x 8 chunks
        const int cb = c - 1024;
        const int row = cb >> 3;
        const int scc = (cb & 7) ^ (row & 7);
        load_lds16(W + (size_t)(tn + row) * K + k0 + scc * 8, &Bs[buf][cb * 8]);
      }
    }
  };

  f32x4 acc[2][2] = {};
  const int nsteps = K / 64;           // 16

  stage(0, 0);

#pragma unroll 1
  for (int ks = 0; ks < nsteps; ++ks) {
    // own stage(ks) loads were issued a full compute-phase ago -> near-free wait
    asm volatile("s_waitcnt vmcnt(0)" ::: "memory");
    __builtin_amdgcn_sched_barrier(0);
    __builtin_amdgcn_s_barrier();       // stage(ks) visible to all waves
    __builtin_amdgcn_sched_barrier(0);
    const int cur = ks & 1;
    if (ks + 1 < nsteps) stage((ks + 1) * 64, cur ^ 1);

#pragma unroll
    for (int kh = 0; kh < 2; ++kh) {
      bf16x8 af[2], bw[2];
#pragma unroll
      for (int i = 0; i < 2; ++i) {
        const int row = wr + i * 16 + l15;
        af[i] = *reinterpret_cast<const bf16x8*>(
            &As[cur][row * 64 + (((kh * 4 + lg) ^ (row & 7)) * 8)]);
      }
#pragma unroll
      for (int j = 0; j < 2; ++j) {
        const int row = wc + j * 16 + l15;
        bw[j] = *reinterpret_cast<const bf16x8*>(
            &Bs[cur][row * 64 + (((kh * 4 + lg) ^ (row & 7)) * 8)]);
      }
#pragma unroll
      for (int i = 0; i < 2; ++i)
#pragma unroll
        for (int j = 0; j < 2; ++j)
          acc[i][j] = __builtin_amdgcn_mfma_f32_16x16x32_bf16(af[i], bw[j], acc[i][j], 0, 0, 0);
    }
  }

#pragma unroll
  for (int i = 0; i < 2; ++i)
#pragma unroll
    for (int j = 0; j < 2; ++j)
#pragma unroll
      for (int r = 0; r < 4; ++r) {
        const int row = tm + wr + i * 16 + lg * 4 + r;   // C/D: row=(lane>>4)*4+reg
        const int col = tn + wc + j * 16 + l15;          //      col=lane&15
        const float v = (acc[i][j][r] + bias[col]) * oscale;
        if constexpr (MODE == 0) {
          reinterpret_cast<u16*>(Out)[(size_t)row * N + col] = f2bf(v);
        } else if constexpr (MODE == 1) {
          reinterpret_cast<float*>(Out)[(size_t)row * N + col] = v;
        } else {
          const int s_ = row >> 1, b_ = row & 1;
          const int h_ = col >> 6, dh_ = col & 63;
          reinterpret_cast<u16*>(Out)[((size_t)(b_ * 16 + h_) * 64 + dh_) * kS + s_] = f2bf(v);
        }
      }
}

__global__ __launch_bounds__(512, 4) void qkv_gemm(
    const u16* __restrict__ xb,
    const u16* __restrict__ Wqb, const u16* __restrict__ Wkb, const u16* __restrict__ Wvb,
    const float* __restrict__ bq, const float* __restrict__ bk, const float* __restrict__ bv,
    u16* __restrict__ Q, u16* __restrict__ K, u16* __restrict__ Vt) {
  const int z = blockIdx.z;
  if (z == 2) {
    gemm_body<2>(xb, Wvb, bv, Vt, kM, kD, kD, 1.0f);
  } else if (z == 0) {
    // fold softmax scale (in exp2 domain) into Q so attn inner loop is p=exp2(sc)
    gemm_body<0>(xb, Wqb, bq, Q, kM, kD, kD, kScale * kLog2e);
  } else {
    gemm_body<0>(xb, Wkb, bk, K, kM, kD, kD, 1.0f);
  }
}

__global__ __launch_bounds__(512, 4) void out_gemm(
    const u16* __restrict__ Ob, const u16* __restrict__ Wob,
    const float* __restrict__ bo, float* __restrict__ out) {
  gemm_body<1>(Ob, Wob, bo, out, kM, kD, kD, 1.0f);
}

// ---------------- flash attention (R11 exact — best measured: 52.4 us) ----------------
__global__ __launch_bounds__(512, 4) void attn_fwd(
    const u16* __restrict__ Qg, const u16* __restrict__ Kg,
    const u16* __restrict__ Vtg, u16* __restrict__ Og) {
  __shared__ u16 Ksm[2 * 4096];        // [half][64*64] single K buffer, 16 KiB
  __shared__ u16 Vsm[2 * 2 * 4096];    // [half][2 bufs][64*64], 32 KiB

  const int tid = threadIdx.x;
  const int lane = tid & 63;
  const int w = tid >> 6;
  const int half = w >> 2;              // 0: tiles 0..15, 1: tiles 16..31
  const int wsub = w & 3;
  const int ltid = tid & 255;           // thread id within half
  const int l31 = lane & 31;
  const int hi = lane >> 5;

  const int bid = blockIdx.x;           // 512 blocks
  const int xcd = bid & 7;
  const int idx = bid >> 3;             // 0..63
  const int bh = xcd * 4 + (idx & 3);   // each XCD owns 4 bh slices (L2 locality)
  const int qb = idx >> 2;              // 0..15
  const int b = bh & 1;
  const int h = bh >> 1;
  const int hoff = h * kDH;
  const int vslot = b * 16 + h;         // Vt slot (matches GEMM MODE-2 epilogue)
  const int qrow = qb * 128 + wsub * 32 + l31;

  u16* Kh = &Ksm[half * 4096];
  u16* Vh = &Vsm[half * 2 * 4096];

  // Q fragments (B-operand: rows = qrow, k = dh); Q is pre-scaled by kScale*log2e
  bf16x8 qf[4];
#pragma unroll
  for (int ks = 0; ks < 4; ++ks)
    qf[ks] = *reinterpret_cast<const bf16x8*>(
        &Qg[(size_t)(qrow * kB + b) * kD + hoff + ks * 16 + hi * 8]);

  f32x16 acc[2] = {};
  float lac[4] = {0.f, 0.f, 0.f, 0.f};

  auto stage = [&](int t0, int vbuf) {
#pragma unroll
    for (int p = 0; p < 2; ++p) {
      const int c = p * 256 + ltid;  // 0..511 chunks of 16B
      const int row = c >> 3;        // 8 chunks per 64-elem row
      const int scc = (c & 7) ^ (row & 7);
      load_lds16(&Kg[(size_t)((t0 + row) * kB + b) * kD + hoff + scc * 8],
                 &Kh[c * 8]);
      load_lds16(&Vtg[(size_t)(vslot * 64 + row) * kS + t0 + scc * 8],
                 &Vh[vbuf * 4096 + c * 8]);
    }
  };

  const int tbase = half * 16;          // this half's first tile
  stage(tbase * 64, 0);

#pragma unroll 1
  for (int ti = 0; ti < 16; ++ti) {
    asm volatile("s_waitcnt vmcnt(0)" ::: "memory");
    __builtin_amdgcn_sched_barrier(0);
    __builtin_amdgcn_s_barrier();       // bar1: K(ti), V(ti) visible to all waves
    __builtin_amdgcn_sched_barrier(0);

    // ---- QK^T = mfma(K, Q): lane owns q-row l31, t = crow(reg,hi) ----
    f32x16 sc[2] = {};
    __builtin_amdgcn_s_setprio(1);
#pragma unroll
    for (int nb = 0; nb < 2; ++nb) {
      const int krow = nb * 32 + l31;
#pragma unroll
      for (int ks = 0; ks < 4; ++ks) {
        const bf16x8 kf = *reinterpret_cast<const bf16x8*>(
            &Kh[krow * 64 + (((ks * 2 + hi) ^ (krow & 7)) * 8)]);
        sc[nb] = __builtin_amdgcn_mfma_f32_32x32x16_bf16(kf, qf[ks], sc[nb], 0, 0, 0);
      }
    }
    __builtin_amdgcn_s_setprio(0);

    __builtin_amdgcn_sched_barrier(0);
    __builtin_amdgcn_s_barrier();       // bar2: every wave's K reads retired
    __builtin_amdgcn_sched_barrier(0);
    if (ti + 1 < 16) stage((tbase + ti + 1) * 64, (ti + 1) & 1);

    const int cur = ti & 1;

    // ---- no-max softmax: p = exp2(sc)  (Q pre-scaled; constant bias cancels) ----
    bf16x8 pb[4];
#pragma unroll
    for (int nb = 0; nb < 2; ++nb) {
      float p[16];
#pragma unroll
      for (int r = 0; r < 16; ++r) {
        p[r] = exp2_hw(sc[nb][r]);
        lac[r & 3] += p[r];
      }
      u32 pk[4][2];
#pragma unroll
      for (int q = 0; q < 4; ++q)
#pragma unroll
        for (int w2 = 0; w2 < 2; ++w2)
          pk[q][w2] = pack2(p[4 * q + 2 * w2], p[4 * q + 2 * w2 + 1]);
#pragma unroll
      for (int k1 = 0; k1 < 2; ++k1) {
        u32 a0 = pk[2 * k1][0], b0 = pk[2 * k1 + 1][0];
        u32 a1 = pk[2 * k1][1], b1 = pk[2 * k1 + 1][1];
        permswap(a0, b0);
        permswap(a1, b1);
        union { u32 wv[4]; bf16x8 v; } U;
        U.wv[0] = a0; U.wv[1] = a1; U.wv[2] = b0; U.wv[3] = b1;
        pb[2 * nb + k1] = U.v;
      }
    }

    // ---- PV: acc(O^T) += mfma(Vt, P) ----
    __builtin_amdgcn_s_setprio(1);
#pragma unroll
    for (int ks = 0; ks < 4; ++ks)
#pragma unroll
      for (int n2 = 0; n2 < 2; ++n2) {
        const int vrow = n2 * 32 + l31;
        const bf16x8 va = *reinterpret_cast<const bf16x8*>(
            &Vh[cur * 4096 + vrow * 64 + (((ks * 2 + hi) ^ (vrow & 7)) * 8)]);
        acc[n2] = __builtin_amdgcn_mfma_f32_32x32x16_bf16(va, pb[ks], acc[n2], 0, 0, 0);
      }
    __builtin_amdgcn_s_setprio(0);
  }

  // ---- cross-half combine via LDS (partials additive thanks to fixed m) ----
  __syncthreads();   // all compute done; LDS buffers retired
  float* Ocmb = reinterpret_cast<float*>(&Vsm[0]);   // 128*64 f32 = 32 KiB (fits Vsm)
  float* Lcmb = reinterpret_cast<float*>(&Ksm[0]);   // 128 f32 (fits Ksm)
  const float l_own = (lac[0] + lac[1]) + (lac[2] + lac[3]);
  const float l_half = l_own + __shfl_xor(l_own, 32);
  const int q = wsub * 32 + l31;

  if (half == 1) {
    if (hi == 0) Lcmb[q] = l_half;
#pragma unroll
    for (int n2 = 0; n2 < 2; ++n2)
#pragma unroll
      for (int q4 = 0; q4 < 4; ++q4)
#pragma unroll
        for (int rp = 0; rp < 2; ++rp) {
          const int dh0 = n2 * 32 + q4 * 8 + hi * 4 + rp * 2;
          const int a = q * 64 + (dh0 ^ ((l31 & 7) << 3));   // bank-spread XOR
          *reinterpret_cast<float2*>(&Ocmb[a]) =
              make_float2(acc[n2][q4 * 4 + rp * 2], acc[n2][q4 * 4 + rp * 2 + 1]);
        }
  }
  __syncthreads();
  if (half == 0) {
    const float inv = 1.0f / (l_half + Lcmb[q]);
#pragma unroll
    for (int n2 = 0; n2 < 2; ++n2)
#pragma unroll
      for (int q4 = 0; q4 < 4; ++q4)
#pragma unroll
        for (int rp = 0; rp < 2; ++rp) {
          const int dh0 = n2 * 32 + q4 * 8 + hi * 4 + rp * 2;
          const int a = q * 64 + (dh0 ^ ((l31 & 7) << 3));
          const float2 o = *reinterpret_cast<const float2*>(&Ocmb[a]);
          acc[n2][q4 * 4 + rp * 2]     += o.x;
          acc[n2][q4 * 4 + rp * 2 + 1] += o.y;
        }
    // store: lane holds O[qrow][dh = n2*32 + 8*g + 4*hi + j] -> 8B packed stores
#pragma unroll
    for (int n2 = 0; n2 < 2; ++n2)
#pragma unroll
      for (int g = 0; g < 4; ++g) {
        const int dh0 = n2 * 32 + g * 8 + hi * 4;
        ushort4 o;
        o.x = f2bf(acc[n2][g * 4 + 0] * inv);
        o.y = f2bf(acc[n2][g * 4 + 1] * inv);
        o.z = f2bf(acc[n2][g * 4 + 2] * inv);
        o.w = f2bf(acc[n2][g * 4 + 3] * inv);
        *reinterpret_cast<ushort4*>(&Og[(size_t)(qrow * kB + b) * kD + hoff + dh0]) = o;
      }
  }
}

// ---------------- launcher ----------------
extern "C" void kernel_launch(void* const* d_in, const int* in_sizes, int n_in,
                              void* d_out, int out_size, void* d_ws, size_t ws_size,
                              hipStream_t stream) {
  const float* x  = (const float*)d_in[0];
  const float* Wq = (const float*)d_in[1];
  const float* bq = (const float*)d_in[2];
  const float* Wk = (const float*)d_in[3];
  const float* bk = (const float*)d_in[4];
  const float* Wv = (const float*)d_in[5];
  const float* bv = (const float*)d_in[6];
  const float* Wo = (const float*)d_in[7];
  const float* bo = (const float*)d_in[8];
  float* out = (float*)d_out;

  char* ws = (char*)d_ws;
  u16* xb  = (u16*)(ws + 0);           // 4096x1024 bf16  (8 MiB)
  u16* Wqb = (u16*)(ws + 8388608);     // 1024x1024 bf16  (2 MiB each)
  u16* Wkb = (u16*)(ws + 10485760);
  u16* Wvb = (u16*)(ws + 12582912);
  u16* Wob = (u16*)(ws + 14680064);
  u16* Qb  = (u16*)(ws + 16777216);    // 4096x1024 bf16
  u16* Kb  = (u16*)(ws + 25165824);
  u16* Vtb = (u16*)(ws + 33554432);    // Vt[32 slots=(b*16+h)][64 dh][2048 s] bf16 (8 MiB)
  u16* Ob  = (u16*)(ws + 41943040);    // end 50331648 (48 MiB)

  cast_all<<<8192, 256, 0, stream>>>(x, Wq, Wk, Wv, Wo, xb, Wqb, Wkb, Wvb, Wob);

  qkv_gemm<<<dim3(kM / 128, kD / 64, 3), 512, 0, stream>>>(
      xb, Wqb, Wkb, Wvb, bq, bk, bv, Qb, Kb, Vtb);

  attn_fwd<<<512, 512, 0, stream>>>(Qb, Kb, Vtb, Ob);

  out_gemm<<<dim3(kM / 128, kD / 64), 512, 0, stream>>>(Ob, Wob, bo, out);
}

// Round 16
// 109.839 us; speedup vs baseline: 1.3700x; 1.3700x over previous
//
#include <hip/hip_runtime.h>
#include <hip/hip_bf16.h>

typedef unsigned short u16;
typedef unsigned int u32;
typedef __bf16 bf16x8 __attribute__((ext_vector_type(8)));
typedef float f32x4 __attribute__((ext_vector_type(4)));
typedef float f32x16 __attribute__((ext_vector_type(16)));

static constexpr int kS = 2048;
static constexpr int kB = 2;
static constexpr int kD = 1024;
static constexpr int kDH = 64;
static constexpr int kM = kS * kB;  // 4096 rows of (s,b)
static constexpr float kScale = 0.125f;   // 1/sqrt(64)
static constexpr float kLog2e = 1.44269504088896340736f;

__device__ __forceinline__ u16 f2bf(float f) {
  return __builtin_bit_cast(u16, static_cast<__bf16>(f));
}

__device__ __forceinline__ u32 pack2(float lo, float hi) {
  union { u16 h[2]; u32 u; } x;
  x.h[0] = f2bf(lo); x.h[1] = f2bf(hi);
  return x.u;
}

__device__ __forceinline__ void permswap(u32& a, u32& b) {
  asm volatile("v_permlane32_swap_b32 %0, %1" : "+v"(a), "+v"(b));
}

// exact hardware exp2 (1 instruction; libm exp2f carries range-fixup ops)
__device__ __forceinline__ float exp2_hw(float x) {
  float r;
  asm("v_exp_f32 %0, %1" : "=v"(r) : "v"(x));
  return r;
}

__device__ __forceinline__ void load_lds16(const void* g, void* l) {
  __builtin_amdgcn_global_load_lds(
      (const __attribute__((address_space(1))) void*)g,
      (__attribute__((address_space(3))) void*)l, 16, 0, 0);
}

// ---------------- fused casts fp32 -> bf16 (one launch) ----------------
__global__ void cast_all(const float* __restrict__ x,
                         const float* __restrict__ Wq, const float* __restrict__ Wk,
                         const float* __restrict__ Wv, const float* __restrict__ Wo,
                         u16* __restrict__ xb,
                         u16* __restrict__ dq, u16* __restrict__ dk,
                         u16* __restrict__ dv, u16* __restrict__ dw) {
  const int bid = blockIdx.x;
  const float* src; u16* dst; int i;
  if (bid < 4096) {
    src = x; dst = xb;
    i = (bid * 256 + (int)threadIdx.x) * 4;
  } else {
    const int r = bid - 4096;
    switch (r >> 10) {
      case 0: src = Wq; dst = dq; break;
      case 1: src = Wk; dst = dk; break;
      case 2: src = Wv; dst = dv; break;
      default: src = Wo; dst = dw; break;
    }
    i = ((r & 1023) * 256 + (int)threadIdx.x) * 4;
  }
  const float4 v = *reinterpret_cast<const float4*>(src + i);
  ushort4 o;
  o.x = f2bf(v.x); o.y = f2bf(v.y); o.z = f2bf(v.z); o.w = f2bf(v.w);
  *reinterpret_cast<ushort4*>(dst + i) = o;
}

// ---------------- GEMM 128x64 tile, double-buffered, 1 barrier per K-step ----------
// LDS buffers are OWNED BY THE KERNEL and passed in: __shared__ inside a templated
// device fn allocates once PER INSTANTIATION (R15 counter: 98304 = 2x48K -> 1
// block/CU). With kernel-scope buffers all MODE instantiations share one 48 KiB
// allocation -> 3 blocks/CU (24 waves).
// Loop (attn-R11 shape): prologue stage(0); per iter
//   [vmcnt(0) (own stage(ks) loads issued a full compute-phase ago -> near-free);
//    s_barrier; stage(ks+1) -> buf^1; ds_read + 8 MFMA from buf]
// 8 waves as 4 row-groups x 2 col-groups; wave = 32x32 out (acc[2][2], 16 VGPR).
// MODE 0: bf16 row-major. MODE 1: f32 row-major. MODE 2: bf16 Vt-transposed.
template <int MODE>
__device__ __forceinline__ void gemm_body(
    u16* __restrict__ AsB, u16* __restrict__ BsB,   // [2][128*64], [2][64*64]
    const u16* __restrict__ A, const u16* __restrict__ W,
    const float* __restrict__ bias, void* __restrict__ Out,
    int M, int N, int K, float oscale) {
  const int tid = threadIdx.x;
  const int lane = tid & 63;
  const int wid = tid >> 6;            // 0..7
  const int wr = (wid >> 1) * 32;      // 4 row-groups
  const int wc = (wid & 1) * 32;       // 2 col-groups
  const int l15 = lane & 15;
  const int lg = lane >> 4;            // 0..3
  const int tm = blockIdx.x * 128;
  const int tn = blockIdx.y * 64;

  auto stage = [&](int k0, int buf) {
#pragma unroll
    for (int p = 0; p < 3; ++p) {
      const int c = p * 512 + tid;      // 0..1535 chunks of 16B
      if (c < 1024) {                   // A: 128 rows x 8 chunks
        const int row = c >> 3;
        const int scc = (c & 7) ^ (row & 7);
        load_lds16(A + (size_t)(tm + row) * K + k0 + scc * 8, &AsB[buf * 8192 + c * 8]);
      } else {                          // B: 64 rows x 8 chunks
        const int cb = c - 1024;
        const int row = cb >> 3;
        const int scc = (cb & 7) ^ (row & 7);
        load_lds16(W + (size_t)(tn + row) * K + k0 + scc * 8, &BsB[buf * 4096 + cb * 8]);
      }
    }
  };

  f32x4 acc[2][2] = {};
  const int nsteps = K / 64;           // 16

  stage(0, 0);

#pragma unroll 1
  for (int ks = 0; ks < nsteps; ++ks) {
    // own stage(ks) loads were issued a full compute-phase ago -> near-free wait
    asm volatile("s_waitcnt vmcnt(0)" ::: "memory");
    __builtin_amdgcn_sched_barrier(0);
    __builtin_amdgcn_s_barrier();       // stage(ks) visible to all waves
    __builtin_amdgcn_sched_barrier(0);
    const int cur = ks & 1;
    if (ks + 1 < nsteps) stage((ks + 1) * 64, cur ^ 1);

    const u16* as = &AsB[cur * 8192];
    const u16* bs = &BsB[cur * 4096];
#pragma unroll
    for (int kh = 0; kh < 2; ++kh) {
      bf16x8 af[2], bw[2];
#pragma unroll
      for (int i = 0; i < 2; ++i) {
        const int row = wr + i * 16 + l15;
        af[i] = *reinterpret_cast<const bf16x8*>(
            &as[row * 64 + (((kh * 4 + lg) ^ (row & 7)) * 8)]);
      }
#pragma unroll
      for (int j = 0; j < 2; ++j) {
        const int row = wc + j * 16 + l15;
        bw[j] = *reinterpret_cast<const bf16x8*>(
            &bs[row * 64 + (((kh * 4 + lg) ^ (row & 7)) * 8)]);
      }
#pragma unroll
      for (int i = 0; i < 2; ++i)
#pragma unroll
        for (int j = 0; j < 2; ++j)
          acc[i][j] = __builtin_amdgcn_mfma_f32_16x16x32_bf16(af[i], bw[j], acc[i][j], 0, 0, 0);
    }
  }

#pragma unroll
  for (int i = 0; i < 2; ++i)
#pragma unroll
    for (int j = 0; j < 2; ++j)
#pragma unroll
      for (int r = 0; r < 4; ++r) {
        const int row = tm + wr + i * 16 + lg * 4 + r;   // C/D: row=(lane>>4)*4+reg
        const int col = tn + wc + j * 16 + l15;          //      col=lane&15
        const float v = (acc[i][j][r] + bias[col]) * oscale;
        if constexpr (MODE == 0) {
          reinterpret_cast<u16*>(Out)[(size_t)row * N + col] = f2bf(v);
        } else if constexpr (MODE == 1) {
          reinterpret_cast<float*>(Out)[(size_t)row * N + col] = v;
        } else {
          const int s_ = row >> 1, b_ = row & 1;
          const int h_ = col >> 6, dh_ = col & 63;
          reinterpret_cast<u16*>(Out)[((size_t)(b_ * 16 + h_) * 64 + dh_) * kS + s_] = f2bf(v);
        }
      }
}

__global__ __launch_bounds__(512, 4) void qkv_gemm(
    const u16* __restrict__ xb,
    const u16* __restrict__ Wqb, const u16* __restrict__ Wkb, const u16* __restrict__ Wvb,
    const float* __restrict__ bq, const float* __restrict__ bk, const float* __restrict__ bv,
    u16* __restrict__ Q, u16* __restrict__ K, u16* __restrict__ Vt) {
  __shared__ u16 As[2 * 128 * 64];   // 32 KiB — single allocation shared by all MODEs
  __shared__ u16 Bs[2 * 64 * 64];    // 16 KiB
  const int z = blockIdx.z;
  if (z == 2) {
    gemm_body<2>(As, Bs, xb, Wvb, bv, Vt, kM, kD, kD, 1.0f);
  } else if (z == 0) {
    // fold softmax scale (in exp2 domain) into Q so attn inner loop is p=exp2(sc)
    gemm_body<0>(As, Bs, xb, Wqb, bq, Q, kM, kD, kD, kScale * kLog2e);
  } else {
    gemm_body<0>(As, Bs, xb, Wkb, bk, K, kM, kD, kD, 1.0f);
  }
}

__global__ __launch_bounds__(512, 4) void out_gemm(
    const u16* __restrict__ Ob, const u16* __restrict__ Wob,
    const float* __restrict__ bo, float* __restrict__ out) {
  __shared__ u16 As[2 * 128 * 64];
  __shared__ u16 Bs[2 * 64 * 64];
  gemm_body<1>(As, Bs, Ob, Wob, bo, out, kM, kD, kD, 1.0f);
}

// ---------------- flash attention (R11 exact — best measured: 52.4 us) ----------------
__global__ __launch_bounds__(512, 4) void attn_fwd(
    const u16* __restrict__ Qg, const u16* __restrict__ Kg,
    const u16* __restrict__ Vtg, u16* __restrict__ Og) {
  __shared__ u16 Ksm[2 * 4096];        // [half][64*64] single K buffer, 16 KiB
  __shared__ u16 Vsm[2 * 2 * 4096];    // [half][2 bufs][64*64], 32 KiB

  const int tid = threadIdx.x;
  const int lane = tid & 63;
  const int w = tid >> 6;
  const int half = w >> 2;              // 0: tiles 0..15, 1: tiles 16..31
  const int wsub = w & 3;
  const int ltid = tid & 255;           // thread id within half
  const int l31 = lane & 31;
  const int hi = lane >> 5;

  const int bid = blockIdx.x;           // 512 blocks
  const int xcd = bid & 7;
  const int idx = bid >> 3;             // 0..63
  const int bh = xcd * 4 + (idx & 3);   // each XCD owns 4 bh slices (L2 locality)
  const int qb = idx >> 2;              // 0..15
  const int b = bh & 1;
  const int h = bh >> 1;
  const int hoff = h * kDH;
  const int vslot = b * 16 + h;         // Vt slot (matches GEMM MODE-2 epilogue)
  const int qrow = qb * 128 + wsub * 32 + l31;

  u16* Kh = &Ksm[half * 4096];
  u16* Vh = &Vsm[half * 2 * 4096];

  // Q fragments (B-operand: rows = qrow, k = dh); Q is pre-scaled by kScale*log2e
  bf16x8 qf[4];
#pragma unroll
  for (int ks = 0; ks < 4; ++ks)
    qf[ks] = *reinterpret_cast<const bf16x8*>(
        &Qg[(size_t)(qrow * kB + b) * kD + hoff + ks * 16 + hi * 8]);

  f32x16 acc[2] = {};
  float lac[4] = {0.f, 0.f, 0.f, 0.f};

  auto stage = [&](int t0, int vbuf) {
#pragma unroll
    for (int p = 0; p < 2; ++p) {
      const int c = p * 256 + ltid;  // 0..511 chunks of 16B
      const int row = c >> 3;        // 8 chunks per 64-elem row
      const int scc = (c & 7) ^ (row & 7);
      load_lds16(&Kg[(size_t)((t0 + row) * kB + b) * kD + hoff + scc * 8],
                 &Kh[c * 8]);
      load_lds16(&Vtg[(size_t)(vslot * 64 + row) * kS + t0 + scc * 8],
                 &Vh[vbuf * 4096 + c * 8]);
    }
  };

  const int tbase = half * 16;          // this half's first tile
  stage(tbase * 64, 0);

#pragma unroll 1
  for (int ti = 0; ti < 16; ++ti) {
    asm volatile("s_waitcnt vmcnt(0)" ::: "memory");
    __builtin_amdgcn_sched_barrier(0);
    __builtin_amdgcn_s_barrier();       // bar1: K(ti), V(ti) visible to all waves
    __builtin_amdgcn_sched_barrier(0);

    // ---- QK^T = mfma(K, Q): lane owns q-row l31, t = crow(reg,hi) ----
    f32x16 sc[2] = {};
    __builtin_amdgcn_s_setprio(1);
#pragma unroll
    for (int nb = 0; nb < 2; ++nb) {
      const int krow = nb * 32 + l31;
#pragma unroll
      for (int ks = 0; ks < 4; ++ks) {
        const bf16x8 kf = *reinterpret_cast<const bf16x8*>(
            &Kh[krow * 64 + (((ks * 2 + hi) ^ (krow & 7)) * 8)]);
        sc[nb] = __builtin_amdgcn_mfma_f32_32x32x16_bf16(kf, qf[ks], sc[nb], 0, 0, 0);
      }
    }
    __builtin_amdgcn_s_setprio(0);

    __builtin_amdgcn_sched_barrier(0);
    __builtin_amdgcn_s_barrier();       // bar2: every wave's K reads retired
    __builtin_amdgcn_sched_barrier(0);
    if (ti + 1 < 16) stage((tbase + ti + 1) * 64, (ti + 1) & 1);

    const int cur = ti & 1;

    // ---- no-max softmax: p = exp2(sc)  (Q pre-scaled; constant bias cancels) ----
    bf16x8 pb[4];
#pragma unroll
    for (int nb = 0; nb < 2; ++nb) {
      float p[16];
#pragma unroll
      for (int r = 0; r < 16; ++r) {
        p[r] = exp2_hw(sc[nb][r]);
        lac[r & 3] += p[r];
      }
      u32 pk[4][2];
#pragma unroll
      for (int q = 0; q < 4; ++q)
#pragma unroll
        for (int w2 = 0; w2 < 2; ++w2)
          pk[q][w2] = pack2(p[4 * q + 2 * w2], p[4 * q + 2 * w2 + 1]);
#pragma unroll
      for (int k1 = 0; k1 < 2; ++k1) {
        u32 a0 = pk[2 * k1][0], b0 = pk[2 * k1 + 1][0];
        u32 a1 = pk[2 * k1][1], b1 = pk[2 * k1 + 1][1];
        permswap(a0, b0);
        permswap(a1, b1);
        union { u32 wv[4]; bf16x8 v; } U;
        U.wv[0] = a0; U.wv[1] = a1; U.wv[2] = b0; U.wv[3] = b1;
        pb[2 * nb + k1] = U.v;
      }
    }

    // ---- PV: acc(O^T) += mfma(Vt, P) ----
    __builtin_amdgcn_s_setprio(1);
#pragma unroll
    for (int ks = 0; ks < 4; ++ks)
#pragma unroll
      for (int n2 = 0; n2 < 2; ++n2) {
        const int vrow = n2 * 32 + l31;
        const bf16x8 va = *reinterpret_cast<const bf16x8*>(
            &Vh[cur * 4096 + vrow * 64 + (((ks * 2 + hi) ^ (vrow & 7)) * 8)]);
        acc[n2] = __builtin_amdgcn_mfma_f32_32x32x16_bf16(va, pb[ks], acc[n2], 0, 0, 0);
      }
    __builtin_amdgcn_s_setprio(0);
  }

  // ---- cross-half combine via LDS (partials additive thanks to fixed m) ----
  __syncthreads();   // all compute done; LDS buffers retired
  float* Ocmb = reinterpret_cast<float*>(&Vsm[0]);   // 128*64 f32 = 32 KiB (fits Vsm)
  float* Lcmb = reinterpret_cast<float*>(&Ksm[0]);   // 128 f32 (fits Ksm)
  const float l_own = (lac[0] + lac[1]) + (lac[2] + lac[3]);
  const float l_half = l_own + __shfl_xor(l_own, 32);
  const int q = wsub * 32 + l31;

  if (half == 1) {
    if (hi == 0) Lcmb[q] = l_half;
#pragma unroll
    for (int n2 = 0; n2 < 2; ++n2)
#pragma unroll
      for (int q4 = 0; q4 < 4; ++q4)
#pragma unroll
        for (int rp = 0; rp < 2; ++rp) {
          const int dh0 = n2 * 32 + q4 * 8 + hi * 4 + rp * 2;
          const int a = q * 64 + (dh0 ^ ((l31 & 7) << 3));   // bank-spread XOR
          *reinterpret_cast<float2*>(&Ocmb[a]) =
              make_float2(acc[n2][q4 * 4 + rp * 2], acc[n2][q4 * 4 + rp * 2 + 1]);
        }
  }
  __syncthreads();
  if (half == 0) {
    const float inv = 1.0f / (l_half + Lcmb[q]);
#pragma unroll
    for (int n2 = 0; n2 < 2; ++n2)
#pragma unroll
      for (int q4 = 0; q4 < 4; ++q4)
#pragma unroll
        for (int rp = 0; rp < 2; ++rp) {
          const int dh0 = n2 * 32 + q4 * 8 + hi * 4 + rp * 2;
          const int a = q * 64 + (dh0 ^ ((l31 & 7) << 3));
          const float2 o = *reinterpret_cast<const float2*>(&Ocmb[a]);
          acc[n2][q4 * 4 + rp * 2]     += o.x;
          acc[n2][q4 * 4 + rp * 2 + 1] += o.y;
        }
    // store: lane holds O[qrow][dh = n2*32 + 8*g + 4*hi + j] -> 8B packed stores
#pragma unroll
    for (int n2 = 0; n2 < 2; ++n2)
#pragma unroll
      for (int g = 0; g < 4; ++g) {
        const int dh0 = n2 * 32 + g * 8 + hi * 4;
        ushort4 o;
        o.x = f2bf(acc[n2][g * 4 + 0] * inv);
        o.y = f2bf(acc[n2][g * 4 + 1] * inv);
        o.z = f2bf(acc[n2][g * 4 + 2] * inv);
        o.w = f2bf(acc[n2][g * 4 + 3] * inv);
        *reinterpret_cast<ushort4*>(&Og[(size_t)(qrow * kB + b) * kD + hoff + dh0]) = o;
      }
  }
}

// ---------------- launcher ----------------
extern "C" void kernel_launch(void* const* d_in, const int* in_sizes, int n_in,
                              void* d_out, int out_size, void* d_ws, size_t ws_size,
                              hipStream_t stream) {
  const float* x  = (const float*)d_in[0];
  const float* Wq = (const float*)d_in[1];
  const float* bq = (const float*)d_in[2];
  const float* Wk = (const float*)d_in[3];
  const float* bk = (const float*)d_in[4];
  const float* Wv = (const float*)d_in[5];
  const float* bv = (const float*)d_in[6];
  const float* Wo = (const float*)d_in[7];
  const float* bo = (const float*)d_in[8];
  float* out = (float*)d_out;

  char* ws = (char*)d_ws;
  u16* xb  = (u16*)(ws + 0);           // 4096x1024 bf16  (8 MiB)
  u16* Wqb = (u16*)(ws + 8388608);     // 1024x1024 bf16  (2 MiB each)
  u16* Wkb = (u16*)(ws + 10485760);
  u16* Wvb = (u16*)(ws + 12582912);
  u16* Wob = (u16*)(ws + 14680064);
  u16* Qb  = (u16*)(ws + 16777216);    // 4096x1024 bf16
  u16* Kb  = (u16*)(ws + 25165824);
  u16* Vtb = (u16*)(ws + 33554432);    // Vt[32 slots=(b*16+h)][64 dh][2048 s] bf16 (8 MiB)
  u16* Ob  = (u16*)(ws + 41943040);    // end 50331648 (48 MiB)

  cast_all<<<8192, 256, 0, stream>>>(x, Wq, Wk, Wv, Wo, xb, Wqb, Wkb, Wvb, Wob);

  qkv_gemm<<<dim3(kM / 128, kD / 64, 3), 512, 0, stream>>>(
      xb, Wqb, Wkb, Wvb, bq, bk, bv, Qb, Kb, Vtb);

  attn_fwd<<<512, 512, 0, stream>>>(Qb, Kb, Vtb, Ob);

  out_gemm<<<dim3(kM / 128, kD / 64), 512, 0, stream>>>(Ob, Wob, bo, out);
}